// Round 3
// baseline (382.615 us; speedup 1.0000x reference)
//
#include <hip/hip_runtime.h>
#include <hip/hip_bf16.h>

typedef __attribute__((ext_vector_type(8))) short short8;
typedef __attribute__((ext_vector_type(4))) float float4v;

#define N_NODES 131072
#define E_EDGES 256
#define IN_CH   128
#define OUT_CH  256
#define NBLK    512          // 2 blocks/CU on 256 CUs -> co-resident by capacity
#define NPB     256          // nodes per block
#define TPB     4            // 64-row GEMM tiles per block

// ---------------------------------------------------------------------------
// Fused kernel with a PLAIN-LAUNCH manual grid barrier.
// R1/R2 post-mortem: hipLaunchCooperativeKernel does not survive the
// harness's hipGraph stream capture (launch errors unchecked -> empty graph
// -> output stayed zero; absmax 5.03 == max|ref|). This version uses a
// regular launch (graph-capturable) + atomic arrive/spin barrier.
// Co-residency: __launch_bounds__(256,2) caps VGPR at 256 and LDS is 35 KB,
// so 2 blocks/CU x 256 CUs = 512 blocks all fit. If that assumption ever
// breaks, the spin times out and the block recomputes the full gram from H
// (read-only input) -- degraded to ~10 ms but still CORRECT, never a hang.
// Cross-block data is ONLY gram: device-scope atomicOr writes + agent-scope
// atomic loads after the barrier.
// ---------------------------------------------------------------------------
__global__ __launch_bounds__(256, 2) void k_fused(
    const float* __restrict__ H, const float* __restrict__ U,
    const float* __restrict__ W, const float* __restrict__ bias,
    unsigned* __restrict__ gram, unsigned* __restrict__ bar,
    float* __restrict__ out) {
  __shared__ __hip_bfloat16 A[64 * 136];       // 17408 B (136: bank de-alias)
  __shared__ unsigned gsh[E_EDGES * 8];        //  8192 B
  __shared__ unsigned long long msh[NPB * 4];  //  8192 B
  __shared__ float ssh[64];
  __shared__ float bsh[OUT_CH];
  __shared__ int fb_sh;

  const int tid = threadIdx.x;
  const int wave = tid >> 6, lane = tid & 63;
  const int quad = lane >> 4, c16 = lane & 15;

  // ---- phase A: masks + gram pattern for this block's 256 nodes ----
  const int nbase = blockIdx.x * NPB + wave * 64;
  unsigned r[4][8];
#pragma unroll
  for (int g = 0; g < 4; ++g)
#pragma unroll
    for (int j = 0; j < 8; ++j) r[g][j] = 0u;

  for (int it = 0; it < 16; ++it) {  // 4 nodes/iter -> 16 loads in flight
    const int n0 = nbase + it * 4;
    float v[4][4];
#pragma unroll
    for (int q = 0; q < 4; ++q) {
      const float* row = H + (size_t)(n0 + q) * E_EDGES;
#pragma unroll
      for (int g = 0; g < 4; ++g) v[q][g] = row[lane + g * 64];
    }
#pragma unroll
    for (int q = 0; q < 4; ++q) {
      unsigned long long b0 = __ballot(v[q][0] >= 0.5f);
      unsigned long long b1 = __ballot(v[q][1] >= 0.5f);
      unsigned long long b2 = __ballot(v[q][2] >= 0.5f);
      unsigned long long b3 = __ballot(v[q][3] >= 0.5f);
      if (lane < 4)
        msh[(size_t)(wave * 64 + it * 4 + q) * 4 + lane] =
            (lane == 0) ? b0 : (lane == 1) ? b1 : (lane == 2) ? b2 : b3;
      unsigned w[8] = {(unsigned)b0, (unsigned)(b0 >> 32),
                       (unsigned)b1, (unsigned)(b1 >> 32),
                       (unsigned)b2, (unsigned)(b2 >> 32),
                       (unsigned)b3, (unsigned)(b3 >> 32)};
      const unsigned long long bb[4] = {b0, b1, b2, b3};
#pragma unroll
      for (int g = 0; g < 4; ++g) {
        const unsigned sel = ((unsigned)(bb[g] >> lane) & 1u) ? 0xFFFFFFFFu : 0u;
#pragma unroll
        for (int j = 0; j < 8; ++j) r[g][j] |= w[j] & sel;
      }
    }
  }

  // LDS merge of the 4 waves' gram contributions, then global atomicOr.
  for (int i = tid; i < E_EDGES * 8; i += 256) gsh[i] = 0u;
  __syncthreads();
#pragma unroll
  for (int g = 0; g < 4; ++g)
#pragma unroll
    for (int j = 0; j < 8; ++j)
      if (r[g][j]) atomicOr(&gsh[(g * 64 + lane) * 8 + j], r[g][j]);
  __syncthreads();
  for (int i = tid; i < E_EDGES * 8; i += 256) {
    unsigned v = gsh[i];
    if (v) {
      // racy pre-read safe: gram freshly memset, OR monotone -> stale read
      // only costs an extra atomic.
      unsigned old = gram[i];
      if ((old | v) != old) atomicOr(&gram[i], v);
    }
  }

  // ---- overlap region: work that needs no other block, done before spin ----
  {  // tile-0 U prestage (block-local LDS)
    const int blockRow0 = blockIdx.x * NPB;
#pragma unroll
    for (int i = tid; i < 64 * 32; i += 256) {
      const int row = i >> 5, c4 = i & 31;
      float4 vv = reinterpret_cast<const float4*>(U + (size_t)(blockRow0 + row) * IN_CH)[c4];
      __hip_bfloat16* dst = &A[row * 136 + c4 * 4];
      dst[0] = __float2bfloat16(vv.x);
      dst[1] = __float2bfloat16(vv.y);
      dst[2] = __float2bfloat16(vv.z);
      dst[3] = __float2bfloat16(vv.w);
    }
    bsh[tid] = bias[tid];
  }
  // MFMA B-fragments in registers from fp32 W (read-only input, L2-hot).
  // Identical conversion/layout to the verified two-kernel Wb path:
  // bfrag[nn][ks][j] = bf16(W[ks*32+quad*8+j][wave*64+nn*16+c16]).
  short8 bfrag[4][4];
#pragma unroll
  for (int nn = 0; nn < 4; ++nn) {
    const int col = wave * 64 + nn * 16 + c16;
#pragma unroll
    for (int ks = 0; ks < 4; ++ks) {
      short8 b;
#pragma unroll
      for (int j = 0; j < 8; ++j) {
        const float wv = W[(ks * 32 + quad * 8 + j) * OUT_CH + col];
        b[j] = (short)__builtin_bit_cast(unsigned short, __float2bfloat16(wv));
      }
      bfrag[nn][ks] = b;
    }
  }

  // ---- manual grid barrier (graph-capture-safe) ----
  __syncthreads();  // all phase-A work (incl. gram atomicOrs issued) done
  if (tid == 0) {
    int fb = 0;
    __hip_atomic_fetch_add(bar, 1u, __ATOMIC_ACQ_REL, __HIP_MEMORY_SCOPE_AGENT);
    unsigned spins = 0;
    while (__hip_atomic_load(bar, __ATOMIC_ACQUIRE, __HIP_MEMORY_SCOPE_AGENT) < NBLK) {
      __builtin_amdgcn_s_sleep(8);
      if (++spins > 2000000u) { fb = 1; break; }  // ~0.25 s >> legit ~100 us
    }
    fb_sh = fb;
  }
  __syncthreads();

  if (fb_sh) {
    // Fallback: co-residency assumption broke. Recompute the FULL gram from H
    // locally (slow but correct; no dependence on other blocks).
    for (int i = tid; i < E_EDGES * 8; i += 256) gsh[i] = 0u;
    __syncthreads();
    unsigned r2[4][8];
#pragma unroll
    for (int g = 0; g < 4; ++g)
#pragma unroll
      for (int j = 0; j < 8; ++j) r2[g][j] = 0u;
    const int fn0 = wave * (N_NODES / 4);
    for (int it = 0; it < (N_NODES / 4) / 4; ++it) {
      const int n0 = fn0 + it * 4;
      float v[4][4];
#pragma unroll
      for (int q = 0; q < 4; ++q) {
        const float* row = H + (size_t)(n0 + q) * E_EDGES;
#pragma unroll
        for (int g = 0; g < 4; ++g) v[q][g] = row[lane + g * 64];
      }
#pragma unroll
      for (int q = 0; q < 4; ++q) {
        unsigned long long b0 = __ballot(v[q][0] >= 0.5f);
        unsigned long long b1 = __ballot(v[q][1] >= 0.5f);
        unsigned long long b2 = __ballot(v[q][2] >= 0.5f);
        unsigned long long b3 = __ballot(v[q][3] >= 0.5f);
        unsigned w[8] = {(unsigned)b0, (unsigned)(b0 >> 32),
                         (unsigned)b1, (unsigned)(b1 >> 32),
                         (unsigned)b2, (unsigned)(b2 >> 32),
                         (unsigned)b3, (unsigned)(b3 >> 32)};
        const unsigned long long bb[4] = {b0, b1, b2, b3};
#pragma unroll
        for (int g = 0; g < 4; ++g) {
          const unsigned sel = ((unsigned)(bb[g] >> lane) & 1u) ? 0xFFFFFFFFu : 0u;
#pragma unroll
          for (int j = 0; j < 8; ++j) r2[g][j] |= w[j] & sel;
        }
      }
    }
#pragma unroll
    for (int g = 0; g < 4; ++g)
#pragma unroll
      for (int j = 0; j < 8; ++j)
        if (r2[g][j]) atomicOr(&gsh[(g * 64 + lane) * 8 + j], r2[g][j]);
    __syncthreads();
  } else {
    // Normal path: re-read merged gram at the coherent point (agent scope;
    // bypasses any stale L1/L2 line the phase-A pre-read may have cached).
    for (int i = tid; i < E_EDGES * 8; i += 256)
      gsh[i] = __hip_atomic_load(&gram[i], __ATOMIC_RELAXED, __HIP_MEMORY_SCOPE_AGENT);
  }

  // ---- phase B: 4 GEMM tiles of {64 rows x 256 cols, K=128} ----
  for (int t = 0; t < TPB; ++t) {
    const int blockRow = blockIdx.x * NPB + t * 64;

    if (t > 0) {  // tile 0 staged before the barrier
#pragma unroll
      for (int i = tid; i < 64 * 32; i += 256) {
        const int row = i >> 5, c4 = i & 31;
        float4 vv = reinterpret_cast<const float4*>(U + (size_t)(blockRow + row) * IN_CH)[c4];
        __hip_bfloat16* dst = &A[row * 136 + c4 * 4];
        dst[0] = __float2bfloat16(vv.x);
        dst[1] = __float2bfloat16(vv.y);
        dst[2] = __float2bfloat16(vv.z);
        dst[3] = __float2bfloat16(vv.w);
      }
    }
    __syncthreads();  // A staged; gsh writes visible for the scan below

    // wave 0: per-row scale (reads msh from phase A) while other waves MFMA
    if (tid < 64) {
      const int ln = t * 64 + tid;
      const unsigned long long m0 = msh[ln * 4 + 0];
      const unsigned long long m1 = msh[ln * 4 + 1];
      const unsigned long long m2 = msh[ln * 4 + 2];
      const unsigned long long m3 = msh[ln * 4 + 3];
      int dv = __popcll(m0) + __popcll(m1) + __popcll(m2) + __popcll(m3);
      unsigned o0 = 0, o1 = 0, o2 = 0, o3 = 0, o4 = 0, o5 = 0, o6 = 0, o7 = 0;
      auto scan = [&](unsigned long long bits, int g) {
        while (bits) {
          int tz = __builtin_ctzll(bits);
          bits &= bits - 1;
          const unsigned* gr = &gsh[((g << 6) + tz) * 8];
          o0 |= gr[0]; o1 |= gr[1]; o2 |= gr[2]; o3 |= gr[3];
          o4 |= gr[4]; o5 |= gr[5]; o6 |= gr[6]; o7 |= gr[7];
        }
      };
      scan(m0, 0); scan(m1, 1); scan(m2, 2); scan(m3, 3);
      dv += __popc(o0) + __popc(o1) + __popc(o2) + __popc(o3) +
            __popc(o4) + __popc(o5) + __popc(o6) + __popc(o7);
      float sv = 1.0f;
      if (dv > 0) sv += 1.0f / sqrtf((float)dv);
      ssh[tid] = sv;
    }

    float4v acc[4][4];
#pragma unroll
    for (int m = 0; m < 4; ++m)
#pragma unroll
      for (int nn = 0; nn < 4; ++nn)
        acc[m][nn] = (float4v){0.f, 0.f, 0.f, 0.f};

#pragma unroll
    for (int ks = 0; ks < 4; ++ks) {
      short8 a[4];
#pragma unroll
      for (int m = 0; m < 4; ++m)
        a[m] = *reinterpret_cast<const short8*>(&A[(m * 16 + c16) * 136 + ks * 32 + quad * 8]);
#pragma unroll
      for (int m = 0; m < 4; ++m)
#pragma unroll
        for (int nn = 0; nn < 4; ++nn)
          acc[m][nn] = __builtin_amdgcn_mfma_f32_16x16x32_bf16(a[m], bfrag[nn][ks], acc[m][nn], 0, 0, 0);
    }

    __syncthreads();  // ssh ready + A consumed (safe to restage next tile)

    // epilogue: C/D layout col = lane&15, row = quad*4 + reg
#pragma unroll
    for (int m = 0; m < 4; ++m) {
#pragma unroll
      for (int nn = 0; nn < 4; ++nn) {
        const int col = wave * 64 + nn * 16 + c16;
        const float bv = bsh[col];
#pragma unroll
        for (int rr = 0; rr < 4; ++rr) {
          const int row = m * 16 + quad * 4 + rr;
          out[(size_t)(blockRow + row) * OUT_CH + col] = ssh[row] * acc[m][nn][rr] + bv;
        }
      }
    }
  }
}

// ---------------------------------------------------------------------------
extern "C" void kernel_launch(void* const* d_in, const int* in_sizes, int n_in,
                              void* d_out, int out_size, void* d_ws, size_t ws_size,
                              hipStream_t stream) {
  const float* H    = (const float*)d_in[0];
  const float* U    = (const float*)d_in[1];
  const float* W    = (const float*)d_in[2];
  const float* bias = (const float*)d_in[3];
  float* out = (float*)d_out;

  // ws layout: gram bitmatrix (8 KiB) | barrier counter (cacheline)
  unsigned* gram = (unsigned*)d_ws;
  unsigned* bar  = (unsigned*)((char*)d_ws + 8192);

  hipMemsetAsync(d_ws, 0, 8192 + 64, stream);  // zero gram + barrier counter

  k_fused<<<dim3(NBLK), dim3(256), 0, stream>>>(H, U, W, bias, gram, bar, out);
}